// Round 11
// baseline (129.287 us; speedup 1.0000x reference)
//
#include <hip/hip_runtime.h>
#include <hip/hip_fp16.h>

typedef float f32x4 __attribute__((ext_vector_type(4)));
typedef _Float16 f16x8 __attribute__((ext_vector_type(8)));

#define CDIM 128
#define HW 256
#define NBINS 256
#define BINCAP 2560          // mean fill 1961, sigma ~44 -> +13 sigma headroom
#define TILES_PER_BIN 40     // BINCAP / 64
#define BINS_PER_XCD 32
#define GRID_MAIN 512        // multiple of 8 -> tt&7 invariant per block

// ---- kernel 1: transpose plane (C,H,W) f32 -> (H,W,C) f16 ----
__global__ __launch_bounds__(256) void k_transpose(const float* __restrict__ plane,
                                                   unsigned short* __restrict__ planeT) {
    __shared__ unsigned short tile[32][130];
    int tid = threadIdx.x;
    int y  = blockIdx.x >> 3;
    int x0 = (blockIdx.x & 7) * 32;
    int tx = tid & 31, tc = tid >> 5;
    for (int cc = 0; cc < 128; cc += 8) {
        int c = cc + tc;
        float v = plane[c * (HW * HW) + y * HW + x0 + tx];
        tile[tx][c] = __half_as_ushort(__float2half(v));
    }
    __syncthreads();
    for (int it = 0; it < 16; ++it) {
        int idx = it * 256 + tid;
        int c = idx & 127, xi = idx >> 7;
        planeT[(y * HW + x0 + xi) * CDIM + c] = tile[xi][c];
    }
}

// ---- kernel 2: convert W1,W2 f32 -> f16 ----
__global__ __launch_bounds__(256) void k_wconv(const float* __restrict__ W1,
                                               const float* __restrict__ W2,
                                               unsigned short* __restrict__ W1h,
                                               unsigned short* __restrict__ W2h) {
    int i = blockIdx.x * 256 + threadIdx.x;
    if (i < 16384) W1h[i] = __half_as_ushort(__float2half(W1[i]));
    else           W2h[i - 16384] = __half_as_ushort(__float2half(W2[i - 16384]));
}

// ---- kernel 2b: LDS-aggregated counting scatter into x0 bins ----
// R5's scatter cost ~200us from 500k global atomics on 256 addresses.
// Here: LDS hist per block -> ONE global atomic per bin per block (245/addr).
__global__ __launch_bounds__(256) void k_scatter(const float* __restrict__ coords,
                                                 float4* __restrict__ bins,
                                                 int* __restrict__ cursor, int N) {
    __shared__ int hist[NBINS];
    __shared__ int rnk[NBINS];
    __shared__ int base[NBINS];
    const int tid = threadIdx.x;
    hist[tid] = 0; rnk[tid] = 0;
    __syncthreads();

    const int start = blockIdx.x * 2048;
    float gx[8], gy[8], gz[8]; int bn[8];
#pragma unroll
    for (int k = 0; k < 8; ++k) {
        int p = start + k * 256 + tid;
        if (p < N) {
            gx[k] = coords[p * 3 + 0];
            gy[k] = coords[p * 3 + 1];
            gz[k] = coords[p * 3 + 2];
            float ix = (gx[k] + 1.f) * 127.5f;
            bn[k] = max(0, min((int)floorf(ix), HW - 1));
            atomicAdd(&hist[bn[k]], 1);
        } else bn[k] = -1;
    }
    __syncthreads();
    if (hist[tid] > 0) base[tid] = atomicAdd(&cursor[tid], hist[tid]);
    __syncthreads();
#pragma unroll
    for (int k = 0; k < 8; ++k) {
        if (bn[k] >= 0) {
            int p = start + k * 256 + tid;
            int r = atomicAdd(&rnk[bn[k]], 1);
            int pos = base[bn[k]] + r;
            if (pos < BINCAP) {
                float4 rec; rec.x = gx[k]; rec.y = gy[k]; rec.z = gz[k];
                rec.w = __int_as_float(p);
                bins[(size_t)bn[k] * BINCAP + pos] = rec;
            }
        }
    }
}

// ---- gather helpers ((H,W,C) y-major layout) ----
struct PrepT {
    int off[8];
    __half2 w[4];   // xy bilinear weights
    __half2 v[4];   // xz bilinear weights
};

__device__ __forceinline__ PrepT prepV(float gx, float gy, float gz, int cg) {
    PrepT r;
    float ix = (gx + 1.f) * 127.5f;
    float iy = (gy + 1.f) * 127.5f;
    float iz = (gz + 1.f) * 127.5f;
    float xf = floorf(ix), yf = floorf(iy), zf = floorf(iz);
    float wx1 = ix - xf, wy1 = iy - yf, wz1 = iz - zf;
    float wx0 = 1.f - wx1, wy0 = 1.f - wy1, wz0 = 1.f - wz1;
    int x0 = max(0, min((int)xf, HW - 1));
    int y0 = max(0, min((int)yf, HW - 1));
    int z0 = max(0, min((int)zf, HW - 1));
    int x1 = min(x0 + 1, HW - 1);
    int y1 = min(y0 + 1, HW - 1);
    int z1 = min(z0 + 1, HW - 1);
    int cx0 = x0 * CDIM + cg * 8, cx1 = x1 * CDIM + cg * 8;
    r.off[0] = (y0 << 15) + cx0; r.off[1] = (y0 << 15) + cx1;
    r.off[2] = (y1 << 15) + cx0; r.off[3] = (y1 << 15) + cx1;
    r.off[4] = (z0 << 15) + cx0; r.off[5] = (z0 << 15) + cx1;
    r.off[6] = (z1 << 15) + cx0; r.off[7] = (z1 << 15) + cx1;
    r.w[0] = __float2half2_rn(wy0 * wx0);
    r.w[1] = __float2half2_rn(wy0 * wx1);
    r.w[2] = __float2half2_rn(wy1 * wx0);
    r.w[3] = __float2half2_rn(wy1 * wx1);
    r.v[0] = __float2half2_rn(wz0 * wx0);
    r.v[1] = __float2half2_rn(wz0 * wx1);
    r.v[2] = __float2half2_rn(wz1 * wx0);
    r.v[3] = __float2half2_rn(wz1 * wx1);
    return r;
}

struct LdT { uint4 d[8]; };

__device__ __forceinline__ LdT ld8(const unsigned short* __restrict__ planeT, const PrepT& a) {
    LdT r;
#pragma unroll
    for (int c = 0; c < 8; ++c)
        r.d[c] = *reinterpret_cast<const uint4*>(planeT + a.off[c]);
    return r;
}

__device__ __forceinline__ __half2 geth2(const uint4& u, int g) {
    const unsigned* p = reinterpret_cast<const unsigned*>(&u);
    return __builtin_bit_cast(__half2, p[g]);
}

// packed-f16 interp: 10 pk ops per 2-channel group
__device__ __forceinline__ void interp_store(unsigned short* dst, const PrepT& a, const LdT& L) {
    unsigned o[4];
#pragma unroll
    for (int g = 0; g < 4; ++g) {
        __half2 xy = __hmul2(a.w[0], geth2(L.d[0], g));
        xy = __hfma2(a.w[1], geth2(L.d[1], g), xy);
        xy = __hfma2(a.w[2], geth2(L.d[2], g), xy);
        xy = __hfma2(a.w[3], geth2(L.d[3], g), xy);
        __half2 xz = __hmul2(a.v[0], geth2(L.d[4], g));
        xz = __hfma2(a.v[1], geth2(L.d[5], g), xz);
        xz = __hfma2(a.v[2], geth2(L.d[6], g), xz);
        xz = __hfma2(a.v[3], geth2(L.d[7], g), xz);
        __half2 f = __hmul2(xy, __hmul2(xz, xz));
        o[g] = __builtin_bit_cast(unsigned, f);
    }
    uint4 pack; pack.x = o[0]; pack.y = o[1]; pack.z = o[2]; pack.w = o[3];
    *reinterpret_cast<uint4*>(dst) = pack;
}

// ---- kernel 3: fused gather + MLP over bin-tiles (SORTED) or direct ----
// SORTED: tile index tt -> xcd = tt&7 (invariant per block: grid % 8 == 0),
// bin = xcd*32 + (tt>>3)/TILES_PER_BIN -> each XCD works a contiguous 2MB
// plane slab resident in its L2; instantaneous window ~2-3 bins (~200KB).
// MLP/W-LDS/swizzle structure identical to proven R10 kernel.
template <bool SORTED>
__global__ __launch_bounds__(256, 2) void k_all(const float* __restrict__ coords,
                                                const float4* __restrict__ bins,
                                                const int* __restrict__ cursor,
                                                const unsigned short* __restrict__ planeT,
                                                const unsigned short* __restrict__ W1h,
                                                const unsigned short* __restrict__ W2h,
                                                const float* __restrict__ b1,
                                                const float* __restrict__ b2,
                                                const float* __restrict__ W3,
                                                const float* __restrict__ b3,
                                                float* __restrict__ out, int N) {
    __shared__ alignas(16) uint4 W1L[128][16];              // 32 KB, swizzled
    __shared__ alignas(16) uint4 W2L[128][16];              // 32 KB, swizzled
    __shared__ alignas(16) unsigned short featS[64][128];   // 16 KB, 16B-group swizzle

    const int tid  = threadIdx.x;
    const int wave = tid >> 6, lane = tid & 63;
    const int ro   = wave * 16;
    const int j = lane & 15, rg = lane >> 4;
    const int pt = lane >> 4, cg = lane & 15;   // gather roles

    // stage W into LDS (coalesced global read, swizzled LDS write)
#pragma unroll
    for (int i = 0; i < 8; ++i) {
        int idx = i * 256 + tid;
        int row = idx >> 4, col = idx & 15;
        W1L[row][col ^ (row & 15)] = reinterpret_cast<const uint4*>(W1h)[idx];
        W2L[row][col ^ (row & 15)] = reinterpret_cast<const uint4*>(W2h)[idx];
    }
    float b1v[8], b2v[8], w3v[8];
#pragma unroll
    for (int nt = 0; nt < 8; ++nt) {
        b1v[nt] = b1[nt * 16 + j];
        b2v[nt] = b2[nt * 16 + j];
        w3v[nt] = W3[nt * 16 + j];
    }
    const float bb3 = b3[0];
    __syncthreads();

    const int ntt = SORTED ? (NBINS * TILES_PER_BIN) : ((N + 63) >> 6);
    for (int tt = blockIdx.x; tt < ntt; tt += gridDim.x) {
        int bin = 0, base = 0, cnt = 0, pbase = 0;
        if (SORTED) {
            int xcd = tt & 7, jj = tt >> 3;
            bin  = xcd * BINS_PER_XCD + jj / TILES_PER_BIN;
            base = (jj % TILES_PER_BIN) * 64;
            cnt  = min(cursor[bin], BINCAP);
            if (base >= cnt) continue;   // uniform across block
        } else {
            pbase = tt * 64 + ro;
        }
        const float4* brec = bins + (size_t)bin * BINCAP;

        // -------- phase A: depth-4 gather, 16 points/wave into swizzled featS --------
        {
            PrepT a0, a1, a2, a3;
#pragma unroll
            for (int it = 0; it < 4; ++it) {
                float gx, gy, gz;
                if (SORTED) {
                    int q = min(base + ro + it * 4 + pt, cnt - 1);
                    float4 s = brec[q];
                    gx = s.x; gy = s.y; gz = s.z;
                } else {
                    int p = min(pbase + it * 4 + pt, N - 1);
                    gx = coords[p * 3 + 0];
                    gy = coords[p * 3 + 1];
                    gz = coords[p * 3 + 2];
                }
                PrepT a = prepV(gx, gy, gz, cg);
                if (it == 0) a0 = a; else if (it == 1) a1 = a;
                else if (it == 2) a2 = a; else a3 = a;
            }
            LdT d0 = ld8(planeT, a0);
            LdT d1 = ld8(planeT, a1);
            LdT d2 = ld8(planeT, a2);
            LdT d3 = ld8(planeT, a3);
            interp_store(&featS[ro + 0 * 4 + pt][(cg ^ (0 * 4 + pt)) * 8], a0, d0);
            interp_store(&featS[ro + 1 * 4 + pt][(cg ^ (1 * 4 + pt)) * 8], a1, d1);
            interp_store(&featS[ro + 2 * 4 + pt][(cg ^ (2 * 4 + pt)) * 8], a2, d2);
            interp_store(&featS[ro + 3 * 4 + pt][(cg ^ (3 * 4 + pt)) * 8], a3, d3);
        }

        __syncthreads();   // order feat ds_writes before GEMM1 ds_reads

        // -------- GEMM1: h1 = sin(30*(feat @ W1^T + b1)) --------
        f32x4 acc[8];
#pragma unroll
        for (int nt = 0; nt < 8; ++nt) acc[nt] = (f32x4){0.f, 0.f, 0.f, 0.f};

        f16x8 af[4];
#pragma unroll
        for (int kk = 0; kk < 4; ++kk)
            af[kk] = __builtin_bit_cast(f16x8, *reinterpret_cast<const uint4*>(&featS[ro + j][((kk * 4 + rg) ^ j) * 8]));

#pragma unroll
        for (int kk = 0; kk < 4; ++kk) {
            f16x8 bf[8];
#pragma unroll
            for (int nt = 0; nt < 8; ++nt)
                bf[nt] = __builtin_bit_cast(f16x8, W1L[nt * 16 + j][(kk * 4 + rg) ^ j]);
#pragma unroll
            for (int nt = 0; nt < 8; ++nt)
                acc[nt] = __builtin_amdgcn_mfma_f32_16x16x32_f16(af[kk], bf[nt], acc[nt], 0, 0, 0);
        }

        // h1 overwrites featS rows (wave-private; af already consumed by MFMA)
#pragma unroll
        for (int nt = 0; nt < 8; ++nt) {
#pragma unroll
            for (int r = 0; r < 4; ++r) {
                float h = __sinf(30.f * (acc[nt][r] + b1v[nt]));
                int row = rg * 4 + r;
                int g = (nt * 2 + (j >> 3)) ^ row;
                featS[ro + row][g * 8 + (j & 7)] = __half_as_ushort(__float2half(h));
            }
        }

        __syncthreads();   // order h1 ds_writes before GEMM2 ds_reads

        // -------- GEMM2: h2 = sin(30*(h1 @ W2^T + b2)) --------
        f32x4 acc2[8];
#pragma unroll
        for (int nt = 0; nt < 8; ++nt) acc2[nt] = (f32x4){0.f, 0.f, 0.f, 0.f};

        f16x8 af2[4];
#pragma unroll
        for (int kk = 0; kk < 4; ++kk)
            af2[kk] = __builtin_bit_cast(f16x8, *reinterpret_cast<const uint4*>(&featS[ro + j][((kk * 4 + rg) ^ j) * 8]));

#pragma unroll
        for (int kk = 0; kk < 4; ++kk) {
            f16x8 bf[8];
#pragma unroll
            for (int nt = 0; nt < 8; ++nt)
                bf[nt] = __builtin_bit_cast(f16x8, W2L[nt * 16 + j][(kk * 4 + rg) ^ j]);
#pragma unroll
            for (int nt = 0; nt < 8; ++nt)
                acc2[nt] = __builtin_amdgcn_mfma_f32_16x16x32_f16(af2[kk], bf[nt], acc2[nt], 0, 0, 0);
        }

        // -------- epilogue: out = h2 @ W3^T + b3 --------
        float part[4] = {0.f, 0.f, 0.f, 0.f};
#pragma unroll
        for (int nt = 0; nt < 8; ++nt) {
#pragma unroll
            for (int r = 0; r < 4; ++r)
                part[r] += __sinf(30.f * (acc2[nt][r] + b2v[nt])) * w3v[nt];
        }
#pragma unroll
        for (int off = 1; off < 16; off <<= 1) {
#pragma unroll
            for (int r = 0; r < 4; ++r) part[r] += __shfl_xor(part[r], off, 64);
        }
        if (j == 0) {
#pragma unroll
            for (int r = 0; r < 4; ++r) {
                int pl = rg * 4 + r;
                if (SORTED) {
                    if (base + ro + pl < cnt) {
                        int orig = __float_as_int(brec[base + ro + pl].w);
                        out[orig] = part[r] + bb3;
                    }
                } else {
                    int p = pbase + pl;
                    if (p < N) out[p] = part[r] + bb3;
                }
            }
        }

        __syncthreads();   // protect featS reads from next tile's gather writes
    }
}

extern "C" void kernel_launch(void* const* d_in, const int* in_sizes, int n_in,
                              void* d_out, int out_size, void* d_ws, size_t ws_size,
                              hipStream_t stream) {
    const float* coords = (const float*)d_in[0];
    const float* plane  = (const float*)d_in[1];
    const float* W1     = (const float*)d_in[4];
    const float* b1     = (const float*)d_in[5];
    const float* W2     = (const float*)d_in[6];
    const float* b2     = (const float*)d_in[7];
    const float* W3     = (const float*)d_in[8];
    const float* b3     = (const float*)d_in[9];
    float* out = (float*)d_out;
    int N = in_sizes[0] / 3;

    char* ws = (char*)d_ws;
    unsigned short* planeT = (unsigned short*)ws;                      // 16 MB
    unsigned short* W1h = (unsigned short*)(ws + 16777216);            // 32 KB
    unsigned short* W2h = (unsigned short*)(ws + 16809984);            // 32 KB
    int*    cursor = (int*)(ws + 16842752);                            // 1 KB
    float4* bins   = (float4*)(ws + 16843776);                         // 10 MB
    const size_t need = 16843776 + (size_t)NBINS * BINCAP * 16;

    k_transpose<<<dim3(HW * 8), dim3(256), 0, stream>>>(plane, planeT);
    k_wconv<<<dim3(128), dim3(256), 0, stream>>>(W1, W2, W1h, W2h);

    if (ws_size >= need) {
        hipMemsetAsync(cursor, 0, NBINS * sizeof(int), stream);
        k_scatter<<<dim3((N + 2047) / 2048), dim3(256), 0, stream>>>(coords, bins, cursor, N);
        k_all<true><<<dim3(GRID_MAIN), dim3(256), 0, stream>>>(
            coords, bins, cursor, planeT, W1h, W2h, b1, b2, W3, b3, out, N);
    } else {
        k_all<false><<<dim3(GRID_MAIN), dim3(256), 0, stream>>>(
            coords, bins, cursor, planeT, W1h, W2h, b1, b2, W3, b3, out, N);
    }
}

// Round 12
// 118.207 us; speedup vs baseline: 1.0937x; 1.0937x over previous
//
#include <hip/hip_runtime.h>
#include <hip/hip_fp16.h>

typedef float f32x4 __attribute__((ext_vector_type(4)));
typedef _Float16 f16x8 __attribute__((ext_vector_type(8)));

#define CDIM 128
#define HW 256
#define NBINS 256
#define BINCAP 2560          // mean fill 1961, sigma ~44 -> +13 sigma headroom
#define TILES_PER_BIN 40     // BINCAP / 64
#define BINS_PER_XCD 32
#define GRID_MAIN 512        // multiple of 8 -> tt&7 invariant per block

// Compiler-only memory fence: pins LDS write->read program order (R2/R3
// lesson) without the hardware s_barrier + waitcnt convoy. featS is
// wave-private, so cross-wave sync is NOT needed in the tile loop; hardware
// executes a wave's own DS ops in order.
#define LDS_FENCE() asm volatile("" ::: "memory")

// ---- kernel 1: transpose plane (C,H,W) f32 -> (H,W,C) f16 ----
__global__ __launch_bounds__(256) void k_transpose(const float* __restrict__ plane,
                                                   unsigned short* __restrict__ planeT) {
    __shared__ unsigned short tile[32][130];
    int tid = threadIdx.x;
    int y  = blockIdx.x >> 3;
    int x0 = (blockIdx.x & 7) * 32;
    int tx = tid & 31, tc = tid >> 5;
    for (int cc = 0; cc < 128; cc += 8) {
        int c = cc + tc;
        float v = plane[c * (HW * HW) + y * HW + x0 + tx];
        tile[tx][c] = __half_as_ushort(__float2half(v));
    }
    __syncthreads();
    for (int it = 0; it < 16; ++it) {
        int idx = it * 256 + tid;
        int c = idx & 127, xi = idx >> 7;
        planeT[(y * HW + x0 + xi) * CDIM + c] = tile[xi][c];
    }
}

// ---- kernel 2: convert W1,W2 f32 -> f16 ----
__global__ __launch_bounds__(256) void k_wconv(const float* __restrict__ W1,
                                               const float* __restrict__ W2,
                                               unsigned short* __restrict__ W1h,
                                               unsigned short* __restrict__ W2h) {
    int i = blockIdx.x * 256 + threadIdx.x;
    if (i < 16384) W1h[i] = __half_as_ushort(__float2half(W1[i]));
    else           W2h[i - 16384] = __half_as_ushort(__float2half(W2[i - 16384]));
}

// ---- kernel 2b: LDS-aggregated counting scatter into x0 bins ----
__global__ __launch_bounds__(256) void k_scatter(const float* __restrict__ coords,
                                                 float4* __restrict__ bins,
                                                 int* __restrict__ cursor, int N) {
    __shared__ int hist[NBINS];
    __shared__ int rnk[NBINS];
    __shared__ int base[NBINS];
    const int tid = threadIdx.x;
    hist[tid] = 0; rnk[tid] = 0;
    __syncthreads();

    const int start = blockIdx.x * 2048;
    float gx[8], gy[8], gz[8]; int bn[8];
#pragma unroll
    for (int k = 0; k < 8; ++k) {
        int p = start + k * 256 + tid;
        if (p < N) {
            gx[k] = coords[p * 3 + 0];
            gy[k] = coords[p * 3 + 1];
            gz[k] = coords[p * 3 + 2];
            float ix = (gx[k] + 1.f) * 127.5f;
            bn[k] = max(0, min((int)floorf(ix), HW - 1));
            atomicAdd(&hist[bn[k]], 1);
        } else bn[k] = -1;
    }
    __syncthreads();
    if (hist[tid] > 0) base[tid] = atomicAdd(&cursor[tid], hist[tid]);
    __syncthreads();
#pragma unroll
    for (int k = 0; k < 8; ++k) {
        if (bn[k] >= 0) {
            int p = start + k * 256 + tid;
            int r = atomicAdd(&rnk[bn[k]], 1);
            int pos = base[bn[k]] + r;
            if (pos < BINCAP) {
                float4 rec; rec.x = gx[k]; rec.y = gy[k]; rec.z = gz[k];
                rec.w = __int_as_float(p);
                bins[(size_t)bn[k] * BINCAP + pos] = rec;
            }
        }
    }
}

// ---- gather helpers ((H,W,C) y-major layout) ----
struct PrepT {
    int off[8];
    __half2 w[4];   // xy bilinear weights
    __half2 v[4];   // xz bilinear weights
};

__device__ __forceinline__ PrepT prepV(float gx, float gy, float gz, int cg) {
    PrepT r;
    float ix = (gx + 1.f) * 127.5f;
    float iy = (gy + 1.f) * 127.5f;
    float iz = (gz + 1.f) * 127.5f;
    float xf = floorf(ix), yf = floorf(iy), zf = floorf(iz);
    float wx1 = ix - xf, wy1 = iy - yf, wz1 = iz - zf;
    float wx0 = 1.f - wx1, wy0 = 1.f - wy1, wz0 = 1.f - wz1;
    int x0 = max(0, min((int)xf, HW - 1));
    int y0 = max(0, min((int)yf, HW - 1));
    int z0 = max(0, min((int)zf, HW - 1));
    int x1 = min(x0 + 1, HW - 1);
    int y1 = min(y0 + 1, HW - 1);
    int z1 = min(z0 + 1, HW - 1);
    int cx0 = x0 * CDIM + cg * 8, cx1 = x1 * CDIM + cg * 8;
    r.off[0] = (y0 << 15) + cx0; r.off[1] = (y0 << 15) + cx1;
    r.off[2] = (y1 << 15) + cx0; r.off[3] = (y1 << 15) + cx1;
    r.off[4] = (z0 << 15) + cx0; r.off[5] = (z0 << 15) + cx1;
    r.off[6] = (z1 << 15) + cx0; r.off[7] = (z1 << 15) + cx1;
    r.w[0] = __float2half2_rn(wy0 * wx0);
    r.w[1] = __float2half2_rn(wy0 * wx1);
    r.w[2] = __float2half2_rn(wy1 * wx0);
    r.w[3] = __float2half2_rn(wy1 * wx1);
    r.v[0] = __float2half2_rn(wz0 * wx0);
    r.v[1] = __float2half2_rn(wz0 * wx1);
    r.v[2] = __float2half2_rn(wz1 * wx0);
    r.v[3] = __float2half2_rn(wz1 * wx1);
    return r;
}

struct LdT { uint4 d[8]; };

__device__ __forceinline__ LdT ld8(const unsigned short* __restrict__ planeT, const PrepT& a) {
    LdT r;
#pragma unroll
    for (int c = 0; c < 8; ++c)
        r.d[c] = *reinterpret_cast<const uint4*>(planeT + a.off[c]);
    return r;
}

__device__ __forceinline__ __half2 geth2(const uint4& u, int g) {
    const unsigned* p = reinterpret_cast<const unsigned*>(&u);
    return __builtin_bit_cast(__half2, p[g]);
}

// packed-f16 interp: 10 pk ops per 2-channel group
__device__ __forceinline__ void interp_store(unsigned short* dst, const PrepT& a, const LdT& L) {
    unsigned o[4];
#pragma unroll
    for (int g = 0; g < 4; ++g) {
        __half2 xy = __hmul2(a.w[0], geth2(L.d[0], g));
        xy = __hfma2(a.w[1], geth2(L.d[1], g), xy);
        xy = __hfma2(a.w[2], geth2(L.d[2], g), xy);
        xy = __hfma2(a.w[3], geth2(L.d[3], g), xy);
        __half2 xz = __hmul2(a.v[0], geth2(L.d[4], g));
        xz = __hfma2(a.v[1], geth2(L.d[5], g), xz);
        xz = __hfma2(a.v[2], geth2(L.d[6], g), xz);
        xz = __hfma2(a.v[3], geth2(L.d[7], g), xz);
        __half2 f = __hmul2(xy, __hmul2(xz, xz));
        o[g] = __builtin_bit_cast(unsigned, f);
    }
    uint4 pack; pack.x = o[0]; pack.y = o[1]; pack.z = o[2]; pack.w = o[3];
    *reinterpret_cast<uint4*>(dst) = pack;
}

// ---- kernel 3: fused gather + MLP over bin-tiles (SORTED) or direct ----
// R12 change: per-tile __syncthreads -> compiler-only LDS_FENCE. featS rows
// are wave-private; removing the hardware barriers lets the 8 resident waves
// per CU drift out of phase so gather-VMEM, MFMA and sin-VALU overlap across
// waves. W staging keeps its real barrier (cross-wave edge).
template <bool SORTED>
__global__ __launch_bounds__(256, 2) void k_all(const float* __restrict__ coords,
                                                const float4* __restrict__ bins,
                                                const int* __restrict__ cursor,
                                                const unsigned short* __restrict__ planeT,
                                                const unsigned short* __restrict__ W1h,
                                                const unsigned short* __restrict__ W2h,
                                                const float* __restrict__ b1,
                                                const float* __restrict__ b2,
                                                const float* __restrict__ W3,
                                                const float* __restrict__ b3,
                                                float* __restrict__ out, int N) {
    __shared__ alignas(16) uint4 W1L[128][16];              // 32 KB, swizzled
    __shared__ alignas(16) uint4 W2L[128][16];              // 32 KB, swizzled
    __shared__ alignas(16) unsigned short featS[64][128];   // 16 KB, 16B-group swizzle

    const int tid  = threadIdx.x;
    const int wave = tid >> 6, lane = tid & 63;
    const int ro   = wave * 16;
    const int j = lane & 15, rg = lane >> 4;
    const int pt = lane >> 4, cg = lane & 15;   // gather roles

    // stage W into LDS (coalesced global read, swizzled LDS write)
#pragma unroll
    for (int i = 0; i < 8; ++i) {
        int idx = i * 256 + tid;
        int row = idx >> 4, col = idx & 15;
        W1L[row][col ^ (row & 15)] = reinterpret_cast<const uint4*>(W1h)[idx];
        W2L[row][col ^ (row & 15)] = reinterpret_cast<const uint4*>(W2h)[idx];
    }
    float b1v[8], b2v[8], w3v[8];
#pragma unroll
    for (int nt = 0; nt < 8; ++nt) {
        b1v[nt] = b1[nt * 16 + j];
        b2v[nt] = b2[nt * 16 + j];
        w3v[nt] = W3[nt * 16 + j];
    }
    const float bb3 = b3[0];
    __syncthreads();   // real barrier: W tables are cross-wave

    const int ntt = SORTED ? (NBINS * TILES_PER_BIN) : ((N + 63) >> 6);
    for (int tt = blockIdx.x; tt < ntt; tt += gridDim.x) {
        int bin = 0, base = 0, cnt = 0, pbase = 0;
        if (SORTED) {
            int xcd = tt & 7, jj = tt >> 3;
            bin  = xcd * BINS_PER_XCD + jj / TILES_PER_BIN;
            base = (jj % TILES_PER_BIN) * 64;
            cnt  = min(cursor[bin], BINCAP);
            if (base >= cnt) continue;   // uniform across block
        } else {
            pbase = tt * 64 + ro;
        }
        const float4* brec = bins + (size_t)bin * BINCAP;

        // -------- phase A: depth-4 gather, 16 points/wave into swizzled featS --------
        {
            PrepT a0, a1, a2, a3;
#pragma unroll
            for (int it = 0; it < 4; ++it) {
                float gx, gy, gz;
                if (SORTED) {
                    int q = min(base + ro + it * 4 + pt, cnt - 1);
                    float4 s = brec[q];
                    gx = s.x; gy = s.y; gz = s.z;
                } else {
                    int p = min(pbase + it * 4 + pt, N - 1);
                    gx = coords[p * 3 + 0];
                    gy = coords[p * 3 + 1];
                    gz = coords[p * 3 + 2];
                }
                PrepT a = prepV(gx, gy, gz, cg);
                if (it == 0) a0 = a; else if (it == 1) a1 = a;
                else if (it == 2) a2 = a; else a3 = a;
            }
            LdT d0 = ld8(planeT, a0);
            LdT d1 = ld8(planeT, a1);
            LdT d2 = ld8(planeT, a2);
            LdT d3 = ld8(planeT, a3);
            interp_store(&featS[ro + 0 * 4 + pt][(cg ^ (0 * 4 + pt)) * 8], a0, d0);
            interp_store(&featS[ro + 1 * 4 + pt][(cg ^ (1 * 4 + pt)) * 8], a1, d1);
            interp_store(&featS[ro + 2 * 4 + pt][(cg ^ (2 * 4 + pt)) * 8], a2, d2);
            interp_store(&featS[ro + 3 * 4 + pt][(cg ^ (3 * 4 + pt)) * 8], a3, d3);
        }

        LDS_FENCE();   // order feat ds_writes before GEMM1 ds_reads (compiler)

        // -------- GEMM1: h1 = sin(30*(feat @ W1^T + b1)) --------
        f32x4 acc[8];
#pragma unroll
        for (int nt = 0; nt < 8; ++nt) acc[nt] = (f32x4){0.f, 0.f, 0.f, 0.f};

        f16x8 af[4];
#pragma unroll
        for (int kk = 0; kk < 4; ++kk)
            af[kk] = __builtin_bit_cast(f16x8, *reinterpret_cast<const uint4*>(&featS[ro + j][((kk * 4 + rg) ^ j) * 8]));

#pragma unroll
        for (int kk = 0; kk < 4; ++kk) {
            f16x8 bf[8];
#pragma unroll
            for (int nt = 0; nt < 8; ++nt)
                bf[nt] = __builtin_bit_cast(f16x8, W1L[nt * 16 + j][(kk * 4 + rg) ^ j]);
#pragma unroll
            for (int nt = 0; nt < 8; ++nt)
                acc[nt] = __builtin_amdgcn_mfma_f32_16x16x32_f16(af[kk], bf[nt], acc[nt], 0, 0, 0);
        }

        LDS_FENCE();   // af reads complete before h1 overwrites featS rows

        // h1 overwrites featS rows (wave-private)
#pragma unroll
        for (int nt = 0; nt < 8; ++nt) {
#pragma unroll
            for (int r = 0; r < 4; ++r) {
                float h = __sinf(30.f * (acc[nt][r] + b1v[nt]));
                int row = rg * 4 + r;
                int g = (nt * 2 + (j >> 3)) ^ row;
                featS[ro + row][g * 8 + (j & 7)] = __half_as_ushort(__float2half(h));
            }
        }

        LDS_FENCE();   // order h1 ds_writes before GEMM2 ds_reads (compiler)

        // -------- GEMM2: h2 = sin(30*(h1 @ W2^T + b2)) --------
        f32x4 acc2[8];
#pragma unroll
        for (int nt = 0; nt < 8; ++nt) acc2[nt] = (f32x4){0.f, 0.f, 0.f, 0.f};

        f16x8 af2[4];
#pragma unroll
        for (int kk = 0; kk < 4; ++kk)
            af2[kk] = __builtin_bit_cast(f16x8, *reinterpret_cast<const uint4*>(&featS[ro + j][((kk * 4 + rg) ^ j) * 8]));

#pragma unroll
        for (int kk = 0; kk < 4; ++kk) {
            f16x8 bf[8];
#pragma unroll
            for (int nt = 0; nt < 8; ++nt)
                bf[nt] = __builtin_bit_cast(f16x8, W2L[nt * 16 + j][(kk * 4 + rg) ^ j]);
#pragma unroll
            for (int nt = 0; nt < 8; ++nt)
                acc2[nt] = __builtin_amdgcn_mfma_f32_16x16x32_f16(af2[kk], bf[nt], acc2[nt], 0, 0, 0);
        }

        // -------- epilogue: out = h2 @ W3^T + b3 --------
        float part[4] = {0.f, 0.f, 0.f, 0.f};
#pragma unroll
        for (int nt = 0; nt < 8; ++nt) {
#pragma unroll
            for (int r = 0; r < 4; ++r)
                part[r] += __sinf(30.f * (acc2[nt][r] + b2v[nt])) * w3v[nt];
        }
#pragma unroll
        for (int off = 1; off < 16; off <<= 1) {
#pragma unroll
            for (int r = 0; r < 4; ++r) part[r] += __shfl_xor(part[r], off, 64);
        }
        if (j == 0) {
#pragma unroll
            for (int r = 0; r < 4; ++r) {
                int pl = rg * 4 + r;
                if (SORTED) {
                    if (base + ro + pl < cnt) {
                        int orig = __float_as_int(brec[base + ro + pl].w);
                        out[orig] = part[r] + bb3;
                    }
                } else {
                    int p = pbase + pl;
                    if (p < N) out[p] = part[r] + bb3;
                }
            }
        }

        LDS_FENCE();   // af2 reads complete before next tile's gather writes
    }
}

extern "C" void kernel_launch(void* const* d_in, const int* in_sizes, int n_in,
                              void* d_out, int out_size, void* d_ws, size_t ws_size,
                              hipStream_t stream) {
    const float* coords = (const float*)d_in[0];
    const float* plane  = (const float*)d_in[1];
    const float* W1     = (const float*)d_in[4];
    const float* b1     = (const float*)d_in[5];
    const float* W2     = (const float*)d_in[6];
    const float* b2     = (const float*)d_in[7];
    const float* W3     = (const float*)d_in[8];
    const float* b3     = (const float*)d_in[9];
    float* out = (float*)d_out;
    int N = in_sizes[0] / 3;

    char* ws = (char*)d_ws;
    unsigned short* planeT = (unsigned short*)ws;                      // 16 MB
    unsigned short* W1h = (unsigned short*)(ws + 16777216);            // 32 KB
    unsigned short* W2h = (unsigned short*)(ws + 16809984);            // 32 KB
    int*    cursor = (int*)(ws + 16842752);                            // 1 KB
    float4* bins   = (float4*)(ws + 16843776);                         // 10 MB
    const size_t need = 16843776 + (size_t)NBINS * BINCAP * 16;

    k_transpose<<<dim3(HW * 8), dim3(256), 0, stream>>>(plane, planeT);
    k_wconv<<<dim3(128), dim3(256), 0, stream>>>(W1, W2, W1h, W2h);

    if (ws_size >= need) {
        hipMemsetAsync(cursor, 0, NBINS * sizeof(int), stream);
        k_scatter<<<dim3((N + 2047) / 2048), dim3(256), 0, stream>>>(coords, bins, cursor, N);
        k_all<true><<<dim3(GRID_MAIN), dim3(256), 0, stream>>>(
            coords, bins, cursor, planeT, W1h, W2h, b1, b2, W3, b3, out, N);
    } else {
        k_all<false><<<dim3(GRID_MAIN), dim3(256), 0, stream>>>(
            coords, bins, cursor, planeT, W1h, W2h, b1, b2, W3, b3, out, N);
    }
}